// Round 14
// baseline (231.645 us; speedup 1.0000x reference)
//
#include <hip/hip_runtime.h>
#include <hip/hip_bf16.h>
#include <math.h>

typedef __attribute__((ext_vector_type(8))) short bf16x8;
typedef __attribute__((ext_vector_type(4))) float f32x4;
typedef __attribute__((ext_vector_type(8))) unsigned short u16x8;

__device__ inline float bf2f(unsigned short u) {
    union { float f; unsigned int i; } c; c.i = ((unsigned int)u) << 16; return c.f;
}
__device__ inline unsigned short f2bf(float f) {
    union { float f; unsigned int i; } c; c.f = f;
    unsigned int r = c.i + 0x7fffu + ((c.i >> 16) & 1u);
    return (unsigned short)(r >> 16);
}

// ------- fused prep: x cast + both weight transposes + edge count ----------
__global__ void prep_count(const float* __restrict__ x, unsigned short* __restrict__ xb,
                           const float* __restrict__ W1, unsigned short* __restrict__ W1T,
                           const float* __restrict__ W2, unsigned short* __restrict__ W2T,
                           const int* __restrict__ ei, int* __restrict__ counts,
                           int count4, int E0, int n) {
    int idx = blockIdx.x * blockDim.x + threadIdx.x;
    const int n1 = 128 * 1024;
    const int n2 = 1024 * 64;
    if (idx < count4) {
        float4 v = *(const float4*)&x[(size_t)idx * 4];
        ushort4 o;
        o.x = f2bf(v.x); o.y = f2bf(v.y); o.z = f2bf(v.z); o.w = f2bf(v.w);
        *(ushort4*)&xb[(size_t)idx * 4] = o;
    } else if (idx < count4 + n1) {
        int i1 = idx - count4;
        int nn = i1 / 128, kk = i1 - nn * 128;
        W1T[i1] = f2bf(W1[(size_t)kk * 1024 + nn]);
    } else if (idx < count4 + n1 + n2) {
        int i2 = idx - count4 - n1;
        int nn = i2 / 1024, kk = i2 - nn * 1024;
        W2T[i2] = f2bf(W2[(size_t)kk * 64 + nn]);
    } else {
        int e = idx - count4 - n1 - n2;
        int Etot = E0 + n;
        if (e < Etot) {
            int dst = (e < E0) ? ei[E0 + e] : (e - E0);
            atomicAdd(&counts[dst], 1);
        }
    }
}

// ---------------- single-block wave-shuffle scan ----------------
__global__ void scan_excl(const int* __restrict__ counts, int* __restrict__ offsets, int n) {
    __shared__ int wpre[16];
    __shared__ int total_s;
    __shared__ int running_s;
    int tid = threadIdx.x, lane = tid & 63, w = tid >> 6;
    if (tid == 0) running_s = 0;
    __syncthreads();
    for (int base = 0; base < n; base += 1024) {
        int i = base + tid;
        int v = (i < n) ? counts[i] : 0;
        int incl = v;
        #pragma unroll
        for (int d = 1; d < 64; d <<= 1) {
            int t = __shfl_up(incl, d);
            if (lane >= d) incl += t;
        }
        if (lane == 63) wpre[w] = incl;
        __syncthreads();
        if (w == 0) {
            int s = (lane < 16) ? wpre[lane] : 0;
            int sc = s;
            #pragma unroll
            for (int d = 1; d < 16; d <<= 1) {
                int t = __shfl_up(sc, d);
                if (lane >= d) sc += t;
            }
            if (lane < 16) wpre[lane] = sc - s;
            if (lane == 15) total_s = sc;
        }
        __syncthreads();
        int r = running_s;
        if (i < n) offsets[i] = r + wpre[w] + incl - v;
        __syncthreads();
        if (tid == 0) running_s = r + total_s;
        __syncthreads();
    }
    if (tid == 0) offsets[n] = running_s;
}

// ------- fused: fill_edges (blocks [0,FB)) + layer-1 GEMM (rest) -----------
__global__ __launch_bounds__(256) void fill_gemm1(const int* __restrict__ ei,
                                                  const int* __restrict__ offsets,
                                                  int* __restrict__ cursor,
                                                  int* __restrict__ srcs,
                                                  int E0, int n,
                                                  const unsigned short* __restrict__ A,
                                                  const unsigned short* __restrict__ BT,
                                                  unsigned short* __restrict__ C,
                                                  const float* __restrict__ asrc,
                                                  const float* __restrict__ adst,
                                                  float* __restrict__ es,
                                                  float* __restrict__ ed,
                                                  int M, int FB) {
    int tid = threadIdx.x;
    if ((int)blockIdx.x < FB) {
        int e = blockIdx.x * 256 + tid;
        int Etot = E0 + n;
        if (e >= Etot) return;
        int src, dst;
        if (e < E0) { src = ei[e]; dst = ei[E0 + e]; }
        else        { src = dst = e - E0; }
        int pos = offsets[dst] + atomicAdd(&cursor[dst], 1);
        srcs[pos] = src;
        return;
    }
    const int K = 128, N = 1024;
    int gb = blockIdx.x - FB;
    int bx = gb >> 4, by = gb & 15;
    int wid = tid >> 6, lane = tid & 63;
    int wm = wid >> 1, wn = wid & 1;
    int m0b = bx * 64, n0b = by * 64;
    int m0 = m0b + wm * 32;
    int n0 = n0b + wn * 32;
    int lr = lane & 15;
    int q  = lane >> 4;
    int lk = q * 8;

    int ra0 = min(m0 + lr, M - 1);
    int ra1 = min(m0 + 16 + lr, M - 1);
    const unsigned short* pa[2] = { A + (size_t)ra0 * K + lk, A + (size_t)ra1 * K + lk };
    const unsigned short* pb[2] = { BT + (size_t)(n0 + lr) * K + lk,
                                    BT + (size_t)(n0 + 16 + lr) * K + lk };

    bf16x8 av[2][4], bv[2][4];
    #pragma unroll
    for (int i = 0; i < 2; ++i)
        #pragma unroll
        for (int s = 0; s < 4; ++s) {
            av[i][s] = *(const bf16x8*)(pa[i] + s * 32);
            bv[i][s] = *(const bf16x8*)(pb[i] + s * 32);
        }
    f32x4 acc00 = {0,0,0,0}, acc01 = {0,0,0,0}, acc10 = {0,0,0,0}, acc11 = {0,0,0,0};
    #pragma unroll
    for (int s = 0; s < 4; ++s) {
        acc00 = __builtin_amdgcn_mfma_f32_16x16x32_bf16(av[0][s], bv[0][s], acc00, 0, 0, 0);
        acc01 = __builtin_amdgcn_mfma_f32_16x16x32_bf16(av[0][s], bv[1][s], acc01, 0, 0, 0);
        acc10 = __builtin_amdgcn_mfma_f32_16x16x32_bf16(av[1][s], bv[0][s], acc10, 0, 0, 0);
        acc11 = __builtin_amdgcn_mfma_f32_16x16x32_bf16(av[1][s], bv[1][s], acc11, 0, 0, 0);
    }
    __shared__ unsigned short ct[64][68];
    int srow = q * 4;
    #pragma unroll
    for (int r = 0; r < 4; ++r) {
        ct[wm * 32 + srow + r][wn * 32 + lr]           = f2bf(acc00[r]);
        ct[wm * 32 + srow + r][wn * 32 + 16 + lr]      = f2bf(acc01[r]);
        ct[wm * 32 + 16 + srow + r][wn * 32 + lr]      = f2bf(acc10[r]);
        ct[wm * 32 + 16 + srow + r][wn * 32 + 16 + lr] = f2bf(acc11[r]);
    }
    __syncthreads();
    {
        int row = tid >> 2, cs = (tid & 3) * 16;
        int gr = m0b + row;
        if (gr < M) {
            u16x8 v0, v1;
            #pragma unroll
            for (int j = 0; j < 8; ++j) { v0[j] = ct[row][cs + j]; v1[j] = ct[row][cs + 8 + j]; }
            *(u16x8*)&C[(size_t)gr * N + n0b + cs]     = v0;
            *(u16x8*)&C[(size_t)gr * N + n0b + cs + 8] = v1;
        }
    }
    int head = by * 2 + wn;
    float as_lo = asrc[head * 32 + lr], as_hi = asrc[head * 32 + 16 + lr];
    float ad_lo = adst[head * 32 + lr], ad_hi = adst[head * 32 + 16 + lr];
    #pragma unroll
    for (int X = 0; X < 2; ++X) {
        f32x4 ac0 = X ? acc10 : acc00;
        f32x4 ac1 = X ? acc11 : acc01;
        #pragma unroll
        for (int r = 0; r < 4; ++r) {
            float ps = ac0[r] * as_lo + ac1[r] * as_hi;
            float pd = ac0[r] * ad_lo + ac1[r] * ad_hi;
            #pragma unroll
            for (int msk = 1; msk < 16; msk <<= 1) {
                ps += __shfl_xor(ps, msk);
                pd += __shfl_xor(pd, msk);
            }
            int row = m0 + X * 16 + q * 4 + r;
            if (lr == 0 && row < M) {
                es[row * 32 + head] = ps;
                ed[row * 32 + head] = pd;
            }
        }
    }
}

// ---------------- Layer-2 GEMM, k-split 4 waves + es2/ed2 epilogue --------
__global__ __launch_bounds__(256) void gemm2_fused(const unsigned short* __restrict__ A,
                                                   const unsigned short* __restrict__ BT,
                                                   unsigned short* __restrict__ C,
                                                   const float* __restrict__ asrc,
                                                   const float* __restrict__ adst,
                                                   float* __restrict__ es,
                                                   float* __restrict__ ed, int M) {
    const int K = 1024;
    int tid = threadIdx.x, wid = tid >> 6, lane = tid & 63;
    int m0 = blockIdx.x * 32;
    int lr = lane & 15, q = lane >> 4, lk = q * 8;
    int k0 = wid * 256;

    const unsigned short* pa0 = A + (size_t)(m0 + lr) * K + k0 + lk;
    const unsigned short* pa1 = A + (size_t)(m0 + 16 + lr) * K + k0 + lk;
    const unsigned short* pb0 = BT + (size_t)(0  + lr) * K + k0 + lk;
    const unsigned short* pb1 = BT + (size_t)(16 + lr) * K + k0 + lk;
    const unsigned short* pb2 = BT + (size_t)(32 + lr) * K + k0 + lk;
    const unsigned short* pb3 = BT + (size_t)(48 + lr) * K + k0 + lk;

    f32x4 acc[2][4] = {};
    for (int k = 0; k < 256; k += 64) {
        bf16x8 a0  = *(const bf16x8*)(pa0 + k);
        bf16x8 a1  = *(const bf16x8*)(pa1 + k);
        bf16x8 a0b = *(const bf16x8*)(pa0 + k + 32);
        bf16x8 a1b = *(const bf16x8*)(pa1 + k + 32);
        bf16x8 b0  = *(const bf16x8*)(pb0 + k);
        bf16x8 b0b = *(const bf16x8*)(pb0 + k + 32);
        acc[0][0] = __builtin_amdgcn_mfma_f32_16x16x32_bf16(a0,  b0,  acc[0][0], 0, 0, 0);
        acc[1][0] = __builtin_amdgcn_mfma_f32_16x16x32_bf16(a1,  b0,  acc[1][0], 0, 0, 0);
        acc[0][0] = __builtin_amdgcn_mfma_f32_16x16x32_bf16(a0b, b0b, acc[0][0], 0, 0, 0);
        acc[1][0] = __builtin_amdgcn_mfma_f32_16x16x32_bf16(a1b, b0b, acc[1][0], 0, 0, 0);
        bf16x8 b1  = *(const bf16x8*)(pb1 + k);
        bf16x8 b1b = *(const bf16x8*)(pb1 + k + 32);
        acc[0][1] = __builtin_amdgcn_mfma_f32_16x16x32_bf16(a0,  b1,  acc[0][1], 0, 0, 0);
        acc[1][1] = __builtin_amdgcn_mfma_f32_16x16x32_bf16(a1,  b1,  acc[1][1], 0, 0, 0);
        acc[0][1] = __builtin_amdgcn_mfma_f32_16x16x32_bf16(a0b, b1b, acc[0][1], 0, 0, 0);
        acc[1][1] = __builtin_amdgcn_mfma_f32_16x16x32_bf16(a1b, b1b, acc[1][1], 0, 0, 0);
        bf16x8 b2  = *(const bf16x8*)(pb2 + k);
        bf16x8 b2b = *(const bf16x8*)(pb2 + k + 32);
        acc[0][2] = __builtin_amdgcn_mfma_f32_16x16x32_bf16(a0,  b2,  acc[0][2], 0, 0, 0);
        acc[1][2] = __builtin_amdgcn_mfma_f32_16x16x32_bf16(a1,  b2,  acc[1][2], 0, 0, 0);
        acc[0][2] = __builtin_amdgcn_mfma_f32_16x16x32_bf16(a0b, b2b, acc[0][2], 0, 0, 0);
        acc[1][2] = __builtin_amdgcn_mfma_f32_16x16x32_bf16(a1b, b2b, acc[1][2], 0, 0, 0);
        bf16x8 b3  = *(const bf16x8*)(pb3 + k);
        bf16x8 b3b = *(const bf16x8*)(pb3 + k + 32);
        acc[0][3] = __builtin_amdgcn_mfma_f32_16x16x32_bf16(a0,  b3,  acc[0][3], 0, 0, 0);
        acc[1][3] = __builtin_amdgcn_mfma_f32_16x16x32_bf16(a1,  b3,  acc[1][3], 0, 0, 0);
        acc[0][3] = __builtin_amdgcn_mfma_f32_16x16x32_bf16(a0b, b3b, acc[0][3], 0, 0, 0);
        acc[1][3] = __builtin_amdgcn_mfma_f32_16x16x32_bf16(a1b, b3b, acc[1][3], 0, 0, 0);
    }
    __shared__ float red[4][32][64];
    #pragma unroll
    for (int rf = 0; rf < 2; ++rf)
        #pragma unroll
        for (int cf = 0; cf < 4; ++cf)
            #pragma unroll
            for (int i = 0; i < 4; ++i)
                red[wid][rf * 16 + q * 4 + i][cf * 16 + lr] = acc[rf][cf][i];
    __syncthreads();
    int r = tid >> 3, c0 = (tid & 7) * 8;
    float v[8];
    #pragma unroll
    for (int j = 0; j < 8; ++j)
        v[j] = red[0][r][c0 + j] + red[1][r][c0 + j] + red[2][r][c0 + j] + red[3][r][c0 + j];
    u16x8 o8;
    float ps = 0.f, pd = 0.f;
    #pragma unroll
    for (int j = 0; j < 8; ++j) {
        o8[j] = f2bf(v[j]);
        ps += v[j] * asrc[c0 + j];
        pd += v[j] * adst[c0 + j];
    }
    int row = m0 + r;
    *(u16x8*)&C[(size_t)row * 64 + c0] = o8;
    #pragma unroll
    for (int msk = 1; msk < 8; msk <<= 1) {
        ps += __shfl_xor(ps, msk);
        pd += __shfl_xor(pd, msk);
    }
    if ((tid & 7) == 0) { es[row] = ps; ed[row] = pd; }
}

// ---------------- Layer-1 fused stats+gather: 4 edge-parities, 32B/thread --
// Phase A (h2=tid&31, j2=tid>>5): et -> LDS bf16, partial sums (exp once per
// (edge,head)). Phase B (ep=tid>>6, 64 thr = 32 heads x 16ch): gather 2x16B
// per edge, 2-unroll => 4 loads in flight/thread, 8 edges in flight/block.
__global__ __launch_bounds__(256) void gat1_agg(const unsigned short* __restrict__ hb,
                                                const float* __restrict__ es,
                                                const float* __restrict__ ed,
                                                const int* __restrict__ offsets,
                                                const int* __restrict__ srcs,
                                                const float* __restrict__ b1,
                                                unsigned short* __restrict__ out, int n) {
    int node = blockIdx.x;
    int tid = threadIdx.x;
    int h2 = tid & 31, j2 = tid >> 5;
    int ep = tid >> 6, t2 = tid & 63;
    int head = t2 >> 1, c16 = (t2 & 1) * 16;
    int hoff = head * 32 + c16;

    __shared__ unsigned short lds_et[128][32];
    __shared__ float sed[32];
    __shared__ float red[4][32];
    __shared__ float sinv_s[32];
    __shared__ float comb[3][64][17];

    int beg = offsets[node], end = offsets[node + 1];
    if (tid < 32) sed[tid] = ed[node * 32 + tid];
    __syncthreads();
    float edh = sed[h2];
    float ssum = 0.f;
    float a[16];
    #pragma unroll
    for (int j = 0; j < 16; ++j) a[j] = 0.f;

    for (int c0 = beg; c0 < end; c0 += 128) {
        int lim = min(128, end - c0);
        // phase A: stats into LDS (exp once per (edge,head))
        for (int eloc = j2; eloc < lim; eloc += 8) {
            int s = srcs[c0 + eloc];
            float ev = es[s * 32 + h2] + edh;
            ev = ev > 0.f ? ev : 0.2f * ev;
            unsigned short w16 = f2bf(__expf(ev));
            lds_et[eloc][h2] = w16;
            ssum += bf2f(w16);
        }
        __syncthreads();
        // phase B: 4-parity gather, 32B per edge-thread
        int eloc = ep;
        for (; eloc + 4 < lim; eloc += 8) {
            int s0 = srcs[c0 + eloc], s1 = srcs[c0 + eloc + 4];
            float t0 = bf2f(lds_et[eloc][head]);
            float t1 = bf2f(lds_et[eloc + 4][head]);
            const unsigned short* p0 = &hb[(size_t)s0 * 1024 + hoff];
            const unsigned short* p1 = &hb[(size_t)s1 * 1024 + hoff];
            u16x8 h0a = *(const u16x8*)p0;
            u16x8 h0b = *(const u16x8*)(p0 + 8);
            u16x8 h1a = *(const u16x8*)p1;
            u16x8 h1b = *(const u16x8*)(p1 + 8);
            #pragma unroll
            for (int j = 0; j < 8; ++j) {
                a[j]     += t0 * bf2f(h0a[j]) + t1 * bf2f(h1a[j]);
                a[8 + j] += t0 * bf2f(h0b[j]) + t1 * bf2f(h1b[j]);
            }
        }
        if (eloc < lim) {
            int s0 = srcs[c0 + eloc];
            float t0 = bf2f(lds_et[eloc][head]);
            const unsigned short* p0 = &hb[(size_t)s0 * 1024 + hoff];
            u16x8 h0a = *(const u16x8*)p0;
            u16x8 h0b = *(const u16x8*)(p0 + 8);
            #pragma unroll
            for (int j = 0; j < 8; ++j) {
                a[j]     += t0 * bf2f(h0a[j]);
                a[8 + j] += t0 * bf2f(h0b[j]);
            }
        }
        __syncthreads();
    }

    // sum reduce (stats layout) + parity combine staging
    ssum += __shfl_xor(ssum, 32);
    int w = tid >> 6;
    if ((tid & 63) < 32) red[w][h2] = ssum;
    if (ep > 0) {
        #pragma unroll
        for (int j = 0; j < 16; ++j) comb[ep - 1][t2][j] = a[j];
    }
    __syncthreads();
    if (tid < 32) {
        float s = red[0][tid] + red[1][tid] + red[2][tid] + red[3][tid];
        sinv_s[tid] = 1.0f / (s + 1e-16f);
    }
    __syncthreads();
    if (ep == 0) {
        float si = sinv_s[head];
        u16x8 o8a, o8b;
        #pragma unroll
        for (int j = 0; j < 16; ++j) {
            float r = (a[j] + comb[0][t2][j] + comb[1][t2][j] + comb[2][t2][j]) * si
                      + b1[hoff + j];
            r = r > 0.f ? r : expm1f(r);
            if (j < 8) o8a[j] = f2bf(r); else o8b[j - 8] = f2bf(r);
        }
        *(u16x8*)&out[(size_t)node * 1024 + hoff]     = o8a;
        *(u16x8*)&out[(size_t)node * 1024 + hoff + 8] = o8b;
    }
}

// ---------------- Layer-2 fused stats+gather (wave per node) ---------------
__global__ __launch_bounds__(256) void gat2_agg(const unsigned short* __restrict__ hb2,
                                                const float* __restrict__ es,
                                                const float* __restrict__ ed,
                                                const int* __restrict__ offsets,
                                                const int* __restrict__ srcs,
                                                const float* __restrict__ b2,
                                                float* __restrict__ out, int n) {
    int w = threadIdx.x >> 6;
    int node = blockIdx.x * 4 + w;
    int lane = threadIdx.x & 63;
    __shared__ float lt[4][64];
    if (node >= n) return;
    int beg = offsets[node], end = offsets[node + 1];
    float edv = ed[node];
    float ssum = 0.f, acc = 0.f;
    for (int c0 = beg; c0 < end; c0 += 64) {
        int lim = min(64, end - c0);
        float t = 0.f;
        if (lane < lim) {
            int s = srcs[c0 + lane];
            float ev = es[s] + edv;
            ev = ev > 0.f ? ev : 0.2f * ev;
            t = __expf(ev);
        }
        lt[w][lane] = t;
        ssum += t;
        asm volatile("s_waitcnt lgkmcnt(0)" ::: "memory");
        int jj = 0;
        for (; jj + 3 < lim; jj += 4) {
            int s0 = srcs[c0 + jj], s1 = srcs[c0 + jj + 1];
            int s2 = srcs[c0 + jj + 2], s3 = srcs[c0 + jj + 3];
            acc += lt[w][jj]     * bf2f(hb2[(size_t)s0 * 64 + lane])
                 + lt[w][jj + 1] * bf2f(hb2[(size_t)s1 * 64 + lane])
                 + lt[w][jj + 2] * bf2f(hb2[(size_t)s2 * 64 + lane])
                 + lt[w][jj + 3] * bf2f(hb2[(size_t)s3 * 64 + lane]);
        }
        for (; jj < lim; ++jj) {
            acc += lt[w][jj] * bf2f(hb2[(size_t)srcs[c0 + jj] * 64 + lane]);
        }
    }
    #pragma unroll
    for (int o = 1; o < 64; o <<= 1) ssum += __shfl_xor(ssum, o);
    out[(size_t)node * 64 + lane] = acc * (1.0f / (ssum + 1e-16f)) + b2[lane];
}

// ---------------- launch ----------------
extern "C" void kernel_launch(void* const* d_in, const int* in_sizes, int n_in,
                              void* d_out, int out_size, void* d_ws, size_t ws_size,
                              hipStream_t stream) {
    const float* x        = (const float*)d_in[0];
    const int*   ei       = (const int*)d_in[1];
    const float* W1       = (const float*)d_in[2];
    const float* att_src1 = (const float*)d_in[3];
    const float* att_dst1 = (const float*)d_in[4];
    const float* b1       = (const float*)d_in[5];
    const float* W2       = (const float*)d_in[6];
    const float* att_src2 = (const float*)d_in[7];
    const float* att_dst2 = (const float*)d_in[8];
    const float* b2       = (const float*)d_in[9];
    float* out = (float*)d_out;

    int n  = in_sizes[0] / 128;   // 20000
    int E0 = in_sizes[1] / 2;     // 160000
    int Etot = E0 + n;

    float* ws = (float*)d_ws;
    size_t off = 0;
    unsigned short* hb1 = (unsigned short*)(ws + off); off += (size_t)n * 512;
    unsigned short* hact = (unsigned short*)(ws + off); off += (size_t)n * 512;
    unsigned short* hb2 = (unsigned short*)(ws + off); off += (size_t)n * 32;
    unsigned short* xb  = (unsigned short*)(ws + off); off += (size_t)n * 64;
    unsigned short* W1T = (unsigned short*)(ws + off); off += 1024 * 128 / 2;
    unsigned short* W2T = (unsigned short*)(ws + off); off += 64 * 1024 / 2;
    float* es1  = ws + off; off += (size_t)n * 32;
    float* ed1  = ws + off; off += (size_t)n * 32;
    int* counts  = (int*)(ws + off); off += n;
    int* cursor  = (int*)(ws + off); off += n;
    int* offsets = (int*)(ws + off); off += n + 8;
    int* srcs    = (int*)(ws + off); off += Etot;
    float* es2 = es1;
    float* ed2 = ed1;

    int count4 = n * 128 / 4;
    int prep_total = count4 + 128 * 1024 + 64 * 1024 + Etot;
    int FB = (Etot + 255) / 256;
    int GB = ((n + 63) / 64) * 16;

    hipMemsetAsync(counts, 0, 2 * (size_t)n * sizeof(int), stream);
    prep_count<<<(prep_total + 255) / 256, 256, 0, stream>>>(
        x, xb, W1, W1T, W2, W2T, ei, counts, count4, E0, n);
    scan_excl<<<1, 1024, 0, stream>>>(counts, offsets, n);
    fill_gemm1<<<FB + GB, 256, 0, stream>>>(ei, offsets, cursor, srcs, E0, n,
                                            xb, W1T, hb1, att_src1, att_dst1,
                                            es1, ed1, n, FB);
    gat1_agg<<<n, 256, 0, stream>>>(hb1, es1, ed1, offsets, srcs, b1, hact, n);
    gemm2_fused<<<n / 32, 256, 0, stream>>>(hact, W2T, hb2, att_src2, att_dst2, es2, ed2, n);
    gat2_agg<<<(n + 3) / 4, 256, 0, stream>>>(hb2, es2, ed2, offsets, srcs, b2, out, n);
}

// Round 15
// 192.332 us; speedup vs baseline: 1.2044x; 1.2044x over previous
//
#include <hip/hip_runtime.h>
#include <hip/hip_bf16.h>
#include <math.h>

typedef __attribute__((ext_vector_type(8))) short bf16x8;
typedef __attribute__((ext_vector_type(4))) float f32x4;
typedef __attribute__((ext_vector_type(8))) unsigned short u16x8;

__device__ inline float bf2f(unsigned short u) {
    union { float f; unsigned int i; } c; c.i = ((unsigned int)u) << 16; return c.f;
}
__device__ inline unsigned short f2bf(float f) {
    union { float f; unsigned int i; } c; c.f = f;
    unsigned int r = c.i + 0x7fffu + ((c.i >> 16) & 1u);
    return (unsigned short)(r >> 16);
}

// ------- fused prep: x cast + both weight transposes + edge count ----------
__global__ void prep_count(const float* __restrict__ x, unsigned short* __restrict__ xb,
                           const float* __restrict__ W1, unsigned short* __restrict__ W1T,
                           const float* __restrict__ W2, unsigned short* __restrict__ W2T,
                           const int* __restrict__ ei, int* __restrict__ counts,
                           int count4, int E0, int n) {
    int idx = blockIdx.x * blockDim.x + threadIdx.x;
    const int n1 = 128 * 1024;
    const int n2 = 1024 * 64;
    if (idx < count4) {
        float4 v = *(const float4*)&x[(size_t)idx * 4];
        ushort4 o;
        o.x = f2bf(v.x); o.y = f2bf(v.y); o.z = f2bf(v.z); o.w = f2bf(v.w);
        *(ushort4*)&xb[(size_t)idx * 4] = o;
    } else if (idx < count4 + n1) {
        int i1 = idx - count4;
        int nn = i1 / 128, kk = i1 - nn * 128;
        W1T[i1] = f2bf(W1[(size_t)kk * 1024 + nn]);
    } else if (idx < count4 + n1 + n2) {
        int i2 = idx - count4 - n1;
        int nn = i2 / 1024, kk = i2 - nn * 1024;
        W2T[i2] = f2bf(W2[(size_t)kk * 64 + nn]);
    } else {
        int e = idx - count4 - n1 - n2;
        int Etot = E0 + n;
        if (e < Etot) {
            int dst = (e < E0) ? ei[E0 + e] : (e - E0);
            atomicAdd(&counts[dst], 1);
        }
    }
}

// ---------------- single-block wave-shuffle scan ----------------
__global__ void scan_excl(const int* __restrict__ counts, int* __restrict__ offsets, int n) {
    __shared__ int wpre[16];
    __shared__ int total_s;
    __shared__ int running_s;
    int tid = threadIdx.x, lane = tid & 63, w = tid >> 6;
    if (tid == 0) running_s = 0;
    __syncthreads();
    for (int base = 0; base < n; base += 1024) {
        int i = base + tid;
        int v = (i < n) ? counts[i] : 0;
        int incl = v;
        #pragma unroll
        for (int d = 1; d < 64; d <<= 1) {
            int t = __shfl_up(incl, d);
            if (lane >= d) incl += t;
        }
        if (lane == 63) wpre[w] = incl;
        __syncthreads();
        if (w == 0) {
            int s = (lane < 16) ? wpre[lane] : 0;
            int sc = s;
            #pragma unroll
            for (int d = 1; d < 16; d <<= 1) {
                int t = __shfl_up(sc, d);
                if (lane >= d) sc += t;
            }
            if (lane < 16) wpre[lane] = sc - s;
            if (lane == 15) total_s = sc;
        }
        __syncthreads();
        int r = running_s;
        if (i < n) offsets[i] = r + wpre[w] + incl - v;
        __syncthreads();
        if (tid == 0) running_s = r + total_s;
        __syncthreads();
    }
    if (tid == 0) offsets[n] = running_s;
}

// ------- fused: fill_edges (blocks [0,FB)) + layer-1 GEMM (rest) -----------
__global__ __launch_bounds__(256) void fill_gemm1(const int* __restrict__ ei,
                                                  const int* __restrict__ offsets,
                                                  int* __restrict__ cursor,
                                                  int* __restrict__ srcs,
                                                  int E0, int n,
                                                  const unsigned short* __restrict__ A,
                                                  const unsigned short* __restrict__ BT,
                                                  unsigned short* __restrict__ C,
                                                  const float* __restrict__ asrc,
                                                  const float* __restrict__ adst,
                                                  float* __restrict__ es,
                                                  float* __restrict__ ed,
                                                  int M, int FB) {
    int tid = threadIdx.x;
    if ((int)blockIdx.x < FB) {
        int e = blockIdx.x * 256 + tid;
        int Etot = E0 + n;
        if (e >= Etot) return;
        int src, dst;
        if (e < E0) { src = ei[e]; dst = ei[E0 + e]; }
        else        { src = dst = e - E0; }
        int pos = offsets[dst] + atomicAdd(&cursor[dst], 1);
        srcs[pos] = src;
        return;
    }
    const int K = 128, N = 1024;
    int gb = blockIdx.x - FB;
    int bx = gb >> 4, by = gb & 15;
    int wid = tid >> 6, lane = tid & 63;
    int wm = wid >> 1, wn = wid & 1;
    int m0b = bx * 64, n0b = by * 64;
    int m0 = m0b + wm * 32;
    int n0 = n0b + wn * 32;
    int lr = lane & 15;
    int q  = lane >> 4;
    int lk = q * 8;

    int ra0 = min(m0 + lr, M - 1);
    int ra1 = min(m0 + 16 + lr, M - 1);
    const unsigned short* pa[2] = { A + (size_t)ra0 * K + lk, A + (size_t)ra1 * K + lk };
    const unsigned short* pb[2] = { BT + (size_t)(n0 + lr) * K + lk,
                                    BT + (size_t)(n0 + 16 + lr) * K + lk };

    bf16x8 av[2][4], bv[2][4];
    #pragma unroll
    for (int i = 0; i < 2; ++i)
        #pragma unroll
        for (int s = 0; s < 4; ++s) {
            av[i][s] = *(const bf16x8*)(pa[i] + s * 32);
            bv[i][s] = *(const bf16x8*)(pb[i] + s * 32);
        }
    f32x4 acc00 = {0,0,0,0}, acc01 = {0,0,0,0}, acc10 = {0,0,0,0}, acc11 = {0,0,0,0};
    #pragma unroll
    for (int s = 0; s < 4; ++s) {
        acc00 = __builtin_amdgcn_mfma_f32_16x16x32_bf16(av[0][s], bv[0][s], acc00, 0, 0, 0);
        acc01 = __builtin_amdgcn_mfma_f32_16x16x32_bf16(av[0][s], bv[1][s], acc01, 0, 0, 0);
        acc10 = __builtin_amdgcn_mfma_f32_16x16x32_bf16(av[1][s], bv[0][s], acc10, 0, 0, 0);
        acc11 = __builtin_amdgcn_mfma_f32_16x16x32_bf16(av[1][s], bv[1][s], acc11, 0, 0, 0);
    }
    __shared__ unsigned short ct[64][68];
    int srow = q * 4;
    #pragma unroll
    for (int r = 0; r < 4; ++r) {
        ct[wm * 32 + srow + r][wn * 32 + lr]           = f2bf(acc00[r]);
        ct[wm * 32 + srow + r][wn * 32 + 16 + lr]      = f2bf(acc01[r]);
        ct[wm * 32 + 16 + srow + r][wn * 32 + lr]      = f2bf(acc10[r]);
        ct[wm * 32 + 16 + srow + r][wn * 32 + 16 + lr] = f2bf(acc11[r]);
    }
    __syncthreads();
    {
        int row = tid >> 2, cs = (tid & 3) * 16;
        int gr = m0b + row;
        if (gr < M) {
            u16x8 v0, v1;
            #pragma unroll
            for (int j = 0; j < 8; ++j) { v0[j] = ct[row][cs + j]; v1[j] = ct[row][cs + 8 + j]; }
            *(u16x8*)&C[(size_t)gr * N + n0b + cs]     = v0;
            *(u16x8*)&C[(size_t)gr * N + n0b + cs + 8] = v1;
        }
    }
    int head = by * 2 + wn;
    float as_lo = asrc[head * 32 + lr], as_hi = asrc[head * 32 + 16 + lr];
    float ad_lo = adst[head * 32 + lr], ad_hi = adst[head * 32 + 16 + lr];
    #pragma unroll
    for (int X = 0; X < 2; ++X) {
        f32x4 ac0 = X ? acc10 : acc00;
        f32x4 ac1 = X ? acc11 : acc01;
        #pragma unroll
        for (int r = 0; r < 4; ++r) {
            float ps = ac0[r] * as_lo + ac1[r] * as_hi;
            float pd = ac0[r] * ad_lo + ac1[r] * ad_hi;
            #pragma unroll
            for (int msk = 1; msk < 16; msk <<= 1) {
                ps += __shfl_xor(ps, msk);
                pd += __shfl_xor(pd, msk);
            }
            int row = m0 + X * 16 + q * 4 + r;
            if (lr == 0 && row < M) {
                es[row * 32 + head] = ps;
                ed[row * 32 + head] = pd;
            }
        }
    }
}

// ---------------- Layer-2 GEMM, k-split 4 waves + es2/ed2 epilogue --------
__global__ __launch_bounds__(256) void gemm2_fused(const unsigned short* __restrict__ A,
                                                   const unsigned short* __restrict__ BT,
                                                   unsigned short* __restrict__ C,
                                                   const float* __restrict__ asrc,
                                                   const float* __restrict__ adst,
                                                   float* __restrict__ es,
                                                   float* __restrict__ ed, int M) {
    const int K = 1024;
    int tid = threadIdx.x, wid = tid >> 6, lane = tid & 63;
    int m0 = blockIdx.x * 32;
    int lr = lane & 15, q = lane >> 4, lk = q * 8;
    int k0 = wid * 256;

    const unsigned short* pa0 = A + (size_t)(m0 + lr) * K + k0 + lk;
    const unsigned short* pa1 = A + (size_t)(m0 + 16 + lr) * K + k0 + lk;
    const unsigned short* pb0 = BT + (size_t)(0  + lr) * K + k0 + lk;
    const unsigned short* pb1 = BT + (size_t)(16 + lr) * K + k0 + lk;
    const unsigned short* pb2 = BT + (size_t)(32 + lr) * K + k0 + lk;
    const unsigned short* pb3 = BT + (size_t)(48 + lr) * K + k0 + lk;

    f32x4 acc[2][4] = {};
    for (int k = 0; k < 256; k += 64) {
        bf16x8 a0  = *(const bf16x8*)(pa0 + k);
        bf16x8 a1  = *(const bf16x8*)(pa1 + k);
        bf16x8 a0b = *(const bf16x8*)(pa0 + k + 32);
        bf16x8 a1b = *(const bf16x8*)(pa1 + k + 32);
        bf16x8 b0  = *(const bf16x8*)(pb0 + k);
        bf16x8 b0b = *(const bf16x8*)(pb0 + k + 32);
        acc[0][0] = __builtin_amdgcn_mfma_f32_16x16x32_bf16(a0,  b0,  acc[0][0], 0, 0, 0);
        acc[1][0] = __builtin_amdgcn_mfma_f32_16x16x32_bf16(a1,  b0,  acc[1][0], 0, 0, 0);
        acc[0][0] = __builtin_amdgcn_mfma_f32_16x16x32_bf16(a0b, b0b, acc[0][0], 0, 0, 0);
        acc[1][0] = __builtin_amdgcn_mfma_f32_16x16x32_bf16(a1b, b0b, acc[1][0], 0, 0, 0);
        bf16x8 b1  = *(const bf16x8*)(pb1 + k);
        bf16x8 b1b = *(const bf16x8*)(pb1 + k + 32);
        acc[0][1] = __builtin_amdgcn_mfma_f32_16x16x32_bf16(a0,  b1,  acc[0][1], 0, 0, 0);
        acc[1][1] = __builtin_amdgcn_mfma_f32_16x16x32_bf16(a1,  b1,  acc[1][1], 0, 0, 0);
        acc[0][1] = __builtin_amdgcn_mfma_f32_16x16x32_bf16(a0b, b1b, acc[0][1], 0, 0, 0);
        acc[1][1] = __builtin_amdgcn_mfma_f32_16x16x32_bf16(a1b, b1b, acc[1][1], 0, 0, 0);
        bf16x8 b2  = *(const bf16x8*)(pb2 + k);
        bf16x8 b2b = *(const bf16x8*)(pb2 + k + 32);
        acc[0][2] = __builtin_amdgcn_mfma_f32_16x16x32_bf16(a0,  b2,  acc[0][2], 0, 0, 0);
        acc[1][2] = __builtin_amdgcn_mfma_f32_16x16x32_bf16(a1,  b2,  acc[1][2], 0, 0, 0);
        acc[0][2] = __builtin_amdgcn_mfma_f32_16x16x32_bf16(a0b, b2b, acc[0][2], 0, 0, 0);
        acc[1][2] = __builtin_amdgcn_mfma_f32_16x16x32_bf16(a1b, b2b, acc[1][2], 0, 0, 0);
        bf16x8 b3  = *(const bf16x8*)(pb3 + k);
        bf16x8 b3b = *(const bf16x8*)(pb3 + k + 32);
        acc[0][3] = __builtin_amdgcn_mfma_f32_16x16x32_bf16(a0,  b3,  acc[0][3], 0, 0, 0);
        acc[1][3] = __builtin_amdgcn_mfma_f32_16x16x32_bf16(a1,  b3,  acc[1][3], 0, 0, 0);
        acc[0][3] = __builtin_amdgcn_mfma_f32_16x16x32_bf16(a0b, b3b, acc[0][3], 0, 0, 0);
        acc[1][3] = __builtin_amdgcn_mfma_f32_16x16x32_bf16(a1b, b3b, acc[1][3], 0, 0, 0);
    }
    __shared__ float red[4][32][64];
    #pragma unroll
    for (int rf = 0; rf < 2; ++rf)
        #pragma unroll
        for (int cf = 0; cf < 4; ++cf)
            #pragma unroll
            for (int i = 0; i < 4; ++i)
                red[wid][rf * 16 + q * 4 + i][cf * 16 + lr] = acc[rf][cf][i];
    __syncthreads();
    int r = tid >> 3, c0 = (tid & 7) * 8;
    float v[8];
    #pragma unroll
    for (int j = 0; j < 8; ++j)
        v[j] = red[0][r][c0 + j] + red[1][r][c0 + j] + red[2][r][c0 + j] + red[3][r][c0 + j];
    u16x8 o8;
    float ps = 0.f, pd = 0.f;
    #pragma unroll
    for (int j = 0; j < 8; ++j) {
        o8[j] = f2bf(v[j]);
        ps += v[j] * asrc[c0 + j];
        pd += v[j] * adst[c0 + j];
    }
    int row = m0 + r;
    *(u16x8*)&C[(size_t)row * 64 + c0] = o8;
    #pragma unroll
    for (int msk = 1; msk < 8; msk <<= 1) {
        ps += __shfl_xor(ps, msk);
        pd += __shfl_xor(pd, msk);
    }
    if ((tid & 7) == 0) { es[row] = ps; ed[row] = pd; }
}

// ---------------- Layer-1 fused stats+gather (block per node) --------------
__global__ __launch_bounds__(256) void gat1_agg(const unsigned short* __restrict__ hb,
                                                const float* __restrict__ es,
                                                const float* __restrict__ ed,
                                                const int* __restrict__ offsets,
                                                const int* __restrict__ srcs,
                                                const float* __restrict__ b1,
                                                unsigned short* __restrict__ out, int n) {
    int node = blockIdx.x;
    int tid = threadIdx.x;
    int h2 = tid & 31, j2 = tid >> 5;
    int ep = tid >> 7, t2 = tid & 127;
    int head = t2 >> 2, c8 = (t2 & 3) * 8;
    int hoff = head * 32 + c8;

    __shared__ unsigned short lds_et[128][32];
    __shared__ float sed[32];
    __shared__ float red[4][32];
    __shared__ float sinv_s[32];
    __shared__ float lcomb[128][9];

    int beg = offsets[node], end = offsets[node + 1];
    if (tid < 32) sed[tid] = ed[node * 32 + tid];
    __syncthreads();
    float edh = sed[h2];
    float ssum = 0.f;
    float a[8] = {0.f,0.f,0.f,0.f,0.f,0.f,0.f,0.f};

    for (int c0 = beg; c0 < end; c0 += 128) {
        int lim = min(128, end - c0);
        for (int eloc = j2; eloc < lim; eloc += 8) {
            int s = srcs[c0 + eloc];
            float ev = es[s * 32 + h2] + edh;
            ev = ev > 0.f ? ev : 0.2f * ev;
            unsigned short w16 = f2bf(__expf(ev));
            lds_et[eloc][h2] = w16;
            ssum += bf2f(w16);
        }
        __syncthreads();
        int eloc = ep;
        for (; eloc + 2 < lim; eloc += 4) {
            int s0 = srcs[c0 + eloc], s1 = srcs[c0 + eloc + 2];
            float t0 = bf2f(lds_et[eloc][head]);
            float t1 = bf2f(lds_et[eloc + 2][head]);
            u16x8 h0 = *(const u16x8*)&hb[(size_t)s0 * 1024 + hoff];
            u16x8 h1 = *(const u16x8*)&hb[(size_t)s1 * 1024 + hoff];
            #pragma unroll
            for (int j = 0; j < 8; ++j) a[j] += t0 * bf2f(h0[j]) + t1 * bf2f(h1[j]);
        }
        if (eloc < lim) {
            int s0 = srcs[c0 + eloc];
            float t0 = bf2f(lds_et[eloc][head]);
            u16x8 h0 = *(const u16x8*)&hb[(size_t)s0 * 1024 + hoff];
            #pragma unroll
            for (int j = 0; j < 8; ++j) a[j] += t0 * bf2f(h0[j]);
        }
        __syncthreads();
    }

    ssum += __shfl_xor(ssum, 32);
    int w = tid >> 6;
    if ((tid & 63) < 32) red[w][h2] = ssum;
    if (ep == 1) {
        #pragma unroll
        for (int j = 0; j < 8; ++j) lcomb[t2][j] = a[j];
    }
    __syncthreads();
    if (tid < 32) {
        float s = red[0][tid] + red[1][tid] + red[2][tid] + red[3][tid];
        sinv_s[tid] = 1.0f / (s + 1e-16f);
    }
    __syncthreads();
    if (ep == 0) {
        float si = sinv_s[head];
        float4 bl = *(const float4*)&b1[hoff];
        float4 bh = *(const float4*)&b1[hoff + 4];
        float bb[8] = {bl.x, bl.y, bl.z, bl.w, bh.x, bh.y, bh.z, bh.w};
        u16x8 o8;
        #pragma unroll
        for (int j = 0; j < 8; ++j) {
            float r = (a[j] + lcomb[t2][j]) * si + bb[j];
            r = r > 0.f ? r : expm1f(r);
            o8[j] = f2bf(r);
        }
        *(u16x8*)&out[(size_t)node * 1024 + hoff] = o8;
    }
}

// ---------------- Layer-2 fused stats+gather (wave per node) ---------------
__global__ __launch_bounds__(256) void gat2_agg(const unsigned short* __restrict__ hb2,
                                                const float* __restrict__ es,
                                                const float* __restrict__ ed,
                                                const int* __restrict__ offsets,
                                                const int* __restrict__ srcs,
                                                const float* __restrict__ b2,
                                                float* __restrict__ out, int n) {
    int w = threadIdx.x >> 6;
    int node = blockIdx.x * 4 + w;
    int lane = threadIdx.x & 63;
    __shared__ float lt[4][64];
    if (node >= n) return;
    int beg = offsets[node], end = offsets[node + 1];
    float edv = ed[node];
    float ssum = 0.f, acc = 0.f;
    for (int c0 = beg; c0 < end; c0 += 64) {
        int lim = min(64, end - c0);
        float t = 0.f;
        if (lane < lim) {
            int s = srcs[c0 + lane];
            float ev = es[s] + edv;
            ev = ev > 0.f ? ev : 0.2f * ev;
            t = __expf(ev);
        }
        lt[w][lane] = t;
        ssum += t;
        asm volatile("s_waitcnt lgkmcnt(0)" ::: "memory");
        int jj = 0;
        for (; jj + 3 < lim; jj += 4) {
            int s0 = srcs[c0 + jj], s1 = srcs[c0 + jj + 1];
            int s2 = srcs[c0 + jj + 2], s3 = srcs[c0 + jj + 3];
            acc += lt[w][jj]     * bf2f(hb2[(size_t)s0 * 64 + lane])
                 + lt[w][jj + 1] * bf2f(hb2[(size_t)s1 * 64 + lane])
                 + lt[w][jj + 2] * bf2f(hb2[(size_t)s2 * 64 + lane])
                 + lt[w][jj + 3] * bf2f(hb2[(size_t)s3 * 64 + lane]);
        }
        for (; jj < lim; ++jj) {
            acc += lt[w][jj] * bf2f(hb2[(size_t)srcs[c0 + jj] * 64 + lane]);
        }
    }
    #pragma unroll
    for (int o = 1; o < 64; o <<= 1) ssum += __shfl_xor(ssum, o);
    out[(size_t)node * 64 + lane] = acc * (1.0f / (ssum + 1e-16f)) + b2[lane];
}

// ---------------- launch ----------------
extern "C" void kernel_launch(void* const* d_in, const int* in_sizes, int n_in,
                              void* d_out, int out_size, void* d_ws, size_t ws_size,
                              hipStream_t stream) {
    const float* x        = (const float*)d_in[0];
    const int*   ei       = (const int*)d_in[1];
    const float* W1       = (const float*)d_in[2];
    const float* att_src1 = (const float*)d_in[3];
    const float* att_dst1 = (const float*)d_in[4];
    const float* b1       = (const float*)d_in[5];
    const float* W2       = (const float*)d_in[6];
    const float* att_src2 = (const float*)d_in[7];
    const float* att_dst2 = (const float*)d_in[8];
    const float* b2       = (const float*)d_in[9];
    float* out = (float*)d_out;

    int n  = in_sizes[0] / 128;   // 20000
    int E0 = in_sizes[1] / 2;     // 160000
    int Etot = E0 + n;

    float* ws = (float*)d_ws;
    size_t off = 0;
    unsigned short* hb1 = (unsigned short*)(ws + off); off += (size_t)n * 512;
    unsigned short* hact = (unsigned short*)(ws + off); off += (size_t)n * 512;
    unsigned short* hb2 = (unsigned short*)(ws + off); off += (size_t)n * 32;
    unsigned short* xb  = (unsigned short*)(ws + off); off += (size_t)n * 64;
    unsigned short* W1T = (unsigned short*)(ws + off); off += 1024 * 128 / 2;
    unsigned short* W2T = (unsigned short*)(ws + off); off += 64 * 1024 / 2;
    float* es1  = ws + off; off += (size_t)n * 32;
    float* ed1  = ws + off; off += (size_t)n * 32;
    int* counts  = (int*)(ws + off); off += n;
    int* cursor  = (int*)(ws + off); off += n;
    int* offsets = (int*)(ws + off); off += n + 8;
    int* srcs    = (int*)(ws + off); off += Etot;
    float* es2 = es1;
    float* ed2 = ed1;

    int count4 = n * 128 / 4;
    int prep_total = count4 + 128 * 1024 + 64 * 1024 + Etot;
    int FB = (Etot + 255) / 256;
    int GB = ((n + 63) / 64) * 16;

    hipMemsetAsync(counts, 0, 2 * (size_t)n * sizeof(int), stream);
    prep_count<<<(prep_total + 255) / 256, 256, 0, stream>>>(
        x, xb, W1, W1T, W2, W2T, ei, counts, count4, E0, n);
    scan_excl<<<1, 1024, 0, stream>>>(counts, offsets, n);
    fill_gemm1<<<FB + GB, 256, 0, stream>>>(ei, offsets, cursor, srcs, E0, n,
                                            xb, W1T, hb1, att_src1, att_dst1,
                                            es1, ed1, n, FB);
    gat1_agg<<<n, 256, 0, stream>>>(hb1, es1, ed1, offsets, srcs, b1, hact, n);
    gemm2_fused<<<n / 32, 256, 0, stream>>>(hact, W2T, hb2, att_src2, att_dst2, es2, ed2, n);
    gat2_agg<<<(n + 3) / 4, 256, 0, stream>>>(hb2, es2, ed2, offsets, srcs, b2, out, n);
}